// Round 14
// baseline (778.743 us; speedup 1.0000x reference)
//
#include <hip/hip_runtime.h>

// ---------------- problem constants ----------------
constexpr int NN = 32768;      // nodes
constexpr int EE = 524288;     // edges
constexpr int NB = 256;        // graphs / batch
constexpr int EN = EE + NN;    // edges + self loops

typedef unsigned short u16;
typedef short bh8 __attribute__((ext_vector_type(8)));    // 8 bf16 (4 VGPRs)
typedef float f32x4 __attribute__((ext_vector_type(4)));  // MFMA accumulator

__device__ inline u16 f2b(float f) {   // f32 -> bf16 round-to-nearest-even
  unsigned u = __float_as_uint(f);
  return (u16)((u + 0x7fffu + ((u >> 16) & 1u)) >> 16);
}

// ---------------- workspace layout (bytes) ----------------
constexpr size_t MB = 1ull << 20;
constexpr size_t OFF_A    = 0;        // conv y1 bf16 / h1 [N,320] f32; later MLP partials
constexpr size_t OFF_M1P  = 0;        // c1 partials [3][256*1024] f32 (3MB)
constexpr size_t OFF_M2P  = 4*MB;     // c2 partials [8][256*1024] f32 (8MB)
constexpr size_t OFF_M3P  = 12*MB;    // c3 partials [8][256*512] f32 (4MB)
constexpr size_t OFF_H2B  = 20*MB;    // h2 bf16 [N,96] (6.3MB) for aggr L2 gather
constexpr size_t OFF_B    = 48*MB;    // conv y2 bf16, later g1o [N,320] bf16 (48..69)
constexpr size_t OFF_H1B  = 74*MB;    // h1 bf16 [N,320] (21MB, 74..95) for aggr L1 gather
constexpr size_t OFF_AC   = 100*MB;   // alpha/logits in CSR order [EN,5] f32 (11.2MB)
constexpr size_t OFF_CSRD = 112*MB;   // csr_dst [EN] int (2.2MB)
constexpr size_t OFF_C    = 116*MB;   // h2 [N,96] f32
constexpr size_t OFF_CSRS = 130*MB;   // csr_src [EN]
constexpr size_t OFF_CSRP = 133*MB;   // csr_pos [EN] (edge e -> CSR slot p)
constexpr size_t OFF_ROWP = 136*MB;   // rowptr [N+1]
constexpr size_t OFF_DEG  = 137*MB;   // deg [N]
constexpr size_t OFF_CUR  = 138*MB;   // cursor [N]
constexpr size_t OFF_G2O  = 142*MB;   // g2o [N,96]
constexpr size_t OFF_AS1  = 155*MB;   // [N,5]: attn src terms, then amax
constexpr size_t OFF_AD1  = 156*MB;   // [N,5]: attn dst terms, then rinv
constexpr size_t OFF_AS2  = 157*MB;   // [N]
constexpr size_t OFF_AD2  = 158*MB;
constexpr size_t OFF_CD   = 159*MB;   // [256,96] pooled drug conv
constexpr size_t OFF_CT   = 160*MB;   // [256,96] pooled target conv
constexpr size_t OFF_POOL = 161*MB;   // [256,96] graph pool
constexpr size_t OFF_GFC  = 162*MB;   // [256,96]
constexpr size_t OFF_XC   = 163*MB;   // [256,288]
constexpr size_t OFF_M1B  = 164*MB;   // [256,1024]
constexpr size_t OFF_M2B  = 165*MB;   // [256,1024]
constexpr size_t OFF_M3B  = 166*MB;   // [256,512]
constexpr size_t OFF_FD   = 167*MB;   // F table drug [4][65][32] f32 (k,v,co)
constexpr size_t OFF_FT   = 168*MB;   // F table target [8][26][32] f32 (k,v,co)
constexpr size_t OFF_WD2B = 169*MB;   // drug w2 bf16 [co][kk*32+ci] (64x128)
constexpr size_t OFF_WD3B = 170*MB;   // drug w3 bf16 [co][kk*64+ci] (96x256)
constexpr size_t OFF_WT2B = 171*MB;   // target w2 bf16 [co][kk*32+ci] (64x256)
constexpr size_t OFF_WT3B = 172*MB;   // target w3 bf16 [co][kk*64+ci] (96x512)
constexpr size_t OFF_W2GB = 174*MB;   // g2_w bf16 [co][k] (96x320)
constexpr size_t OFF_CB   = 173*MB;   // const block: [0:25]=M1, [25:30]=M2, [30:35]=easum,
                                      // [35:40]=aeself1, [40]=ae2self, [41:46]=eamean

// =================================================================
// Tiny precompute tables: F_drug [k][v][co], F_target [k][v][co], M1, M2
// =================================================================
__global__ void k_tables(const float* __restrict__ wd1, const float* __restrict__ emb_xd,
                         const float* __restrict__ wt1, const float* __restrict__ emb_xt,
                         const float* __restrict__ g1we, const float* __restrict__ g1ae,
                         const float* __restrict__ g2we, const float* __restrict__ g2ae,
                         float* __restrict__ Fd, float* __restrict__ Ft,
                         float* __restrict__ CB) {
  int t = blockIdx.x * 256 + threadIdx.x;
  const int NFd = 32*4*65, NFt = 32*8*26;
  if (t < NFd) {                       // Fd stored [k][v][co]
    int v = t % 65; int ck = t / 65; int k = ck & 3; int co = ck >> 2;
    float s = 0.f;
    for (int ci = 0; ci < 128; ++ci)
      s = fmaf(wd1[(co*128 + ci)*4 + k], emb_xd[v*128 + ci], s);
    Fd[(k*65 + v)*32 + co] = s;
  } else if (t < NFd + NFt) {          // Ft stored [k][v][co]
    int u = t - NFd;
    int v = u % 26; int ck = u / 26; int k = ck & 7; int co = ck >> 3;
    float s = 0.f;
    for (int ci = 0; ci < 128; ++ci)
      s = fmaf(wt1[(co*128 + ci)*8 + k], emb_xt[v*128 + ci], s);
    Ft[(k*26 + v)*32 + co] = s;
  } else if (t < NFd + NFt + 25) {     // M1[j][h]
    int u = t - NFd - NFt; int h = u % 5, j = u / 5;
    float s = 0.f;
    for (int c = 0; c < 64; ++c)
      s = fmaf(g1we[j*320 + h*64 + c], g1ae[h*64 + c], s);
    CB[j*5 + h] = s;
  } else if (t < NFd + NFt + 30) {     // M2[j]
    int j = t - NFd - NFt - 25;
    float s = 0.f;
    for (int c = 0; c < 96; ++c)
      s = fmaf(g2we[j*96 + c], g2ae[c], s);
    CB[25 + j] = s;
  }
}

// all conv weights + g2_w -> bf16 [co][kk*CIN+ci] layouts
__global__ void k_wcvt(const float* __restrict__ wd2, const float* __restrict__ wd3,
                       const float* __restrict__ wt2, const float* __restrict__ wt3,
                       const float* __restrict__ g2w,
                       u16* __restrict__ od2, u16* __restrict__ od3,
                       u16* __restrict__ ot2, u16* __restrict__ ot3,
                       u16* __restrict__ og2) {
  int t = blockIdx.x*256 + threadIdx.x;
  if (t < 8192) {                       // drug w2: CIN=32,KK=4,CO=64 (KD=128)
    int co = t >> 7, k = t & 127, kk = k >> 5, ci = k & 31;
    od2[t] = f2b(wd2[(co*32 + ci)*4 + kk]);
  } else if ((t -= 8192) < 24576) {     // drug w3: CIN=64,KK=4,CO=96 (KD=256)
    int co = t >> 8, k = t & 255, kk = k >> 6, ci = k & 63;
    od3[t] = f2b(wd3[(co*64 + ci)*4 + kk]);
  } else if ((t -= 24576) < 16384) {    // target w2: CIN=32,KK=8,CO=64 (KD=256)
    int co = t >> 8, k = t & 255, kk = k >> 5, ci = k & 31;
    ot2[t] = f2b(wt2[(co*32 + ci)*8 + kk]);
  } else if ((t -= 16384) < 49152) {    // target w3: CIN=64,KK=8,CO=96 (KD=512)
    int co = t >> 9, k = t & 511, kk = k >> 6, ci = k & 63;
    ot3[t] = f2b(wt3[(co*64 + ci)*8 + kk]);
  } else if ((t -= 49152) < 30720) {    // g2_w: [co][k], k=0..319
    int co = t / 320, k = t % 320;
    og2[t] = f2b(g2w[k*96 + co]);
  }
}

// sum of ea columns -> CB[30..34] (pre-zeroed)
__global__ void k_easum(const float* __restrict__ ea, float* __restrict__ CB) {
  float acc[5] = {0,0,0,0,0};
  for (long e = blockIdx.x*256L + threadIdx.x; e < EE; e += 256L*gridDim.x) {
    #pragma unroll
    for (int j = 0; j < 5; ++j) acc[j] += ea[e*5 + j];
  }
  #pragma unroll
  for (int j = 0; j < 5; ++j)
    for (int off = 1; off < 64; off <<= 1) acc[j] += __shfl_xor(acc[j], off, 64);
  if ((threadIdx.x & 63) == 0) {
    #pragma unroll
    for (int j = 0; j < 5; ++j) atomicAdd(&CB[30 + j], acc[j]);
  }
}

// eamean, aeself1[h], ae2self
__global__ void k_finalize(float* __restrict__ CB) {
  if (blockIdx.x == 0 && threadIdx.x == 0) {
    float em[5];
    for (int j = 0; j < 5; ++j) { em[j] = CB[30 + j] / (float)EE; CB[41 + j] = em[j]; }
    for (int h = 0; h < 5; ++h) {
      float s = 0.f;
      for (int j = 0; j < 5; ++j) s = fmaf(em[j], CB[j*5 + h], s);
      CB[35 + h] = s;
    }
    float s = 0.f;
    for (int j = 0; j < 5; ++j) s = fmaf(em[j], CB[25 + j], s);
    CB[40] = s;
  }
}

// =================================================================
// conv1 via LUT -> bf16 transposed out y[b][l][32]. LUT layout [k][v][32].
// =================================================================
template<int K, int V>
__global__ __launch_bounds__(512) void k_conv1t(
    const int* __restrict__ idx, const float* __restrict__ Ftab,
    const float* __restrict__ bias, u16* __restrict__ y, int L, int Lout) {
  constexpr int CO = 32;
  __shared__ float Fs[K*V*CO];
  __shared__ float bs[CO];
  __shared__ int sq[16 + K];
  int b = blockIdx.y, l0 = blockIdx.x * 16;
  for (int i = threadIdx.x; i < K*V*CO; i += 512) Fs[i] = Ftab[i];
  if (threadIdx.x < CO) bs[threadIdx.x] = bias[threadIdx.x];
  if (threadIdx.x < 16 + K - 1) {
    int l = l0 + (int)threadIdx.x;
    sq[threadIdx.x] = (l < L) ? idx[b*L + l] : 0;
  }
  __syncthreads();
  int co = threadIdx.x & 31;
  int p = threadIdx.x >> 5;
  int l = l0 + p;
  if (l >= Lout) return;
  float acc = bs[co];
  #pragma unroll
  for (int k = 0; k < K; ++k) acc += Fs[(k*V + sq[p + k])*CO + co];
  y[((size_t)b*Lout + l)*CO + co] = f2b(fmaxf(acc, 0.f));
}

// =================================================================
// conv2/conv3 (both branches): implicit-GEMM via MFMA bf16.
// =================================================================
template<int CIN, int KK, int COUT, int NT2, bool POOL>
__global__ __launch_bounds__(512) void k_convmfma(
    const u16* __restrict__ xin, const u16* __restrict__ wtb,
    const float* __restrict__ bias, u16* __restrict__ yout,
    unsigned int* __restrict__ pool, int Lin, int Lout) {
  constexpr int KD = CIN*KK;
  constexpr int NCH = KD/32;
  constexpr int MT = 256, ROWS = MT + KK - 1;
  constexpr int XPAD = CIN + 8;
  constexpr int WPAD = KD + 8;
  __shared__ u16 xs[ROWS*XPAD];
  __shared__ u16 wsd[COUT*WPAD];
  int b = blockIdx.y;
  int l0 = blockIdx.x * MT;
  int tid = threadIdx.x;
  {
    const unsigned* wg = (const unsigned*)wtb;
    unsigned* wl = (unsigned*)wsd;
    constexpr int KD2 = KD/2, WP2 = WPAD/2;
    for (int i = tid; i < COUT*KD2; i += 512) {
      int co = i / KD2, c = i % KD2;
      wl[co*WP2 + c] = wg[i];
    }
  }
  {
    const unsigned* xg = (const unsigned*)(xin + (size_t)b*Lin*CIN);
    unsigned* xl = (unsigned*)xs;
    constexpr int C2 = CIN/2, XP2 = XPAD/2;
    for (int i = tid; i < ROWS*C2; i += 512) {
      int r = i / C2, c = i % C2;
      unsigned v = 0;
      if (l0 + r < Lin) v = xg[(size_t)l0*C2 + i];
      xl[r*XP2 + c] = v;
    }
  }
  __syncthreads();
  int lane = tid & 63;
  int w = tid >> 6;
  int mg = w & 3, ng = w >> 2;
  int l15 = lane & 15, l4 = lane >> 4;
  f32x4 acc[4][NT2];
  #pragma unroll
  for (int mi = 0; mi < 4; ++mi)
    #pragma unroll
    for (int nj = 0; nj < NT2; ++nj) acc[mi][nj] = (f32x4){0.f, 0.f, 0.f, 0.f};

  #pragma unroll
  for (int ch = 0; ch < NCH; ++ch) {
    const int kk = (ch*32) / CIN;
    const int cib = (ch*32) % CIN + l4*8;
    bh8 a[4], bb[NT2];
    #pragma unroll
    for (int mi = 0; mi < 4; ++mi) {
      int row = mg*64 + mi*16 + l15 + kk;
      a[mi] = *(const bh8*)&xs[row*XPAD + cib];
    }
    #pragma unroll
    for (int nj = 0; nj < NT2; ++nj) {
      int co = (ng*NT2 + nj)*16 + l15;
      bb[nj] = *(const bh8*)&wsd[co*WPAD + ch*32 + l4*8];
    }
    #pragma unroll
    for (int mi = 0; mi < 4; ++mi)
      #pragma unroll
      for (int nj = 0; nj < NT2; ++nj)
        acc[mi][nj] = __builtin_amdgcn_mfma_f32_16x16x32_bf16(a[mi], bb[nj], acc[mi][nj], 0, 0, 0);
  }

  if (!POOL) {
    #pragma unroll
    for (int nj = 0; nj < NT2; ++nj) {
      int co = (ng*NT2 + nj)*16 + l15;
      float bv = bias[co];
      #pragma unroll
      for (int mi = 0; mi < 4; ++mi)
        #pragma unroll
        for (int r = 0; r < 4; ++r) {
          int m = mg*64 + mi*16 + l4*4 + r;
          if (l0 + m < Lout)
            yout[((size_t)b*Lout + l0 + m)*COUT + co] = f2b(fmaxf(acc[mi][nj][r] + bv, 0.f));
        }
    }
  } else {
    #pragma unroll
    for (int nj = 0; nj < NT2; ++nj) {
      int co = (ng*NT2 + nj)*16 + l15;
      float bv = bias[co];
      float mx = 0.f;
      #pragma unroll
      for (int mi = 0; mi < 4; ++mi)
        #pragma unroll
        for (int r = 0; r < 4; ++r) {
          int m = mg*64 + mi*16 + l4*4 + r;
          if (l0 + m < Lout) mx = fmaxf(mx, fmaxf(acc[mi][nj][r] + bv, 0.f));
        }
      mx = fmaxf(mx, __shfl_xor(mx, 16, 64));
      mx = fmaxf(mx, __shfl_xor(mx, 32, 64));
      if (l4 == 0) atomicMax(&pool[b*COUT + co], __float_as_uint(mx));
    }
  }
}

// =================================================================
// h2 = g1o(bf16 [N,320]) @ g2_w(bf16 [co][k]) -> f32 h2 + bf16 h2b via MFMA.
// =================================================================
__global__ __launch_bounds__(512) void k_h2mfma(
    const u16* __restrict__ g1ob, const u16* __restrict__ wb,
    float* __restrict__ h2, u16* __restrict__ h2b) {
  constexpr int KD = 320, WPAD = 328, NCH = 10;
  __shared__ u16 wsd[96*WPAD];
  int tid = threadIdx.x;
  {
    const unsigned* wg = (const unsigned*)wb;
    unsigned* wl = (unsigned*)wsd;
    for (int i = tid; i < 96*(KD/2); i += 512) {
      int co = i / (KD/2), c = i % (KD/2);
      wl[co*(WPAD/2) + c] = wg[i];
    }
  }
  __syncthreads();
  int lane = tid & 63;
  int w = tid >> 6;                 // m-sub 0..7
  int l15 = lane & 15, l4 = lane >> 4;
  long m0 = (long)blockIdx.x * 128;
  const u16* xr = g1ob + (m0 + w*16 + l15) * KD;
  f32x4 acc[6];
  #pragma unroll
  for (int nj = 0; nj < 6; ++nj) acc[nj] = (f32x4){0.f, 0.f, 0.f, 0.f};
  #pragma unroll
  for (int ch = 0; ch < NCH; ++ch) {
    bh8 a = *(const bh8*)&xr[ch*32 + l4*8];
    #pragma unroll
    for (int nj = 0; nj < 6; ++nj) {
      bh8 b = *(const bh8*)&wsd[(nj*16 + l15)*WPAD + ch*32 + l4*8];
      acc[nj] = __builtin_amdgcn_mfma_f32_16x16x32_bf16(a, b, acc[nj], 0, 0, 0);
    }
  }
  #pragma unroll
  for (int nj = 0; nj < 6; ++nj) {
    #pragma unroll
    for (int r = 0; r < 4; ++r) {
      long row = m0 + w*16 + l4*4 + r;
      float v = acc[nj][r];
      h2[row*96 + nj*16 + l15] = v;
      h2b[row*96 + nj*16 + l15] = f2b(v);
    }
  }
}

// =================================================================
// register-tiled f32 GEMM (h1) with optional bf16 dual output
// =================================================================
template<int BM, int BN, int BK, int TM, int TN>
__global__ void k_gemm(const float* __restrict__ X, const float* __restrict__ W,
                       float* __restrict__ Y, u16* __restrict__ Yb,
                       int K, int C) {
  constexpr int NTH = (BM/TM)*(BN/TN);
  static_assert(NTH == 256, "block must be 256 threads");
  __shared__ float xs[BK][BM + 1];
  __shared__ float wsm[BK][BN];
  const int m0 = blockIdx.y * BM;
  const int c0 = blockIdx.x * BN;
  const int tn = threadIdx.x % (BN/TN);
  const int tm = threadIdx.x / (BN/TN);
  float acc[TM][TN];
  #pragma unroll
  for (int i = 0; i < TM; ++i)
    #pragma unroll
    for (int j = 0; j < TN; ++j) acc[i][j] = 0.f;

  for (int k0 = 0; k0 < K; k0 += BK) {
    #pragma unroll
    for (int i = threadIdx.x; i < BM*BK; i += NTH) {
      int m = i / BK, k = i % BK;
      xs[k][m] = X[(long)(m0 + m)*K + k0 + k];
    }
    #pragma unroll
    for (int i = threadIdx.x; i < BK*BN; i += NTH) {
      int k = i / BN, c = i % BN;
      wsm[k][c] = W[(long)(k0 + k)*C + c0 + c];
    }
    __syncthreads();
    #pragma unroll
    for (int k = 0; k < BK; ++k) {
      float xv[TM], wv[TN];
      #pragma unroll
      for (int i = 0; i < TM; ++i) xv[i] = xs[k][tm*TM + i];
      #pragma unroll
      for (int j = 0; j < TN; ++j) wv[j] = wsm[k][tn*TN + j];
      #pragma unroll
      for (int i = 0; i < TM; ++i)
        #pragma unroll
        for (int j = 0; j < TN; ++j) acc[i][j] = fmaf(xv[i], wv[j], acc[i][j]);
    }
    __syncthreads();
  }
  #pragma unroll
  for (int i = 0; i < TM; ++i) {
    long row = m0 + tm*TM + i;
    float* yr = Y + row*C + c0 + tn*TN;
    #pragma unroll
    for (int j = 0; j < TN; ++j) {
      float v = acc[i][j];
      yr[j] = v;
      if (Yb) Yb[row*C + c0 + tn*TN + j] = f2b(v);
    }
  }
}

// =================================================================
// split-K f32 GEMM writing PRIVATE per-z partials (no atomics).
// =================================================================
template<int BM, int BN, int BK, int TM, int TN>
__global__ void k_gemm_skp(const float* __restrict__ X, const float* __restrict__ W,
                           float* __restrict__ P, int K, int C, int KS, int MR) {
  constexpr int NTH = (BM/TM)*(BN/TN);
  static_assert(NTH == 256, "block must be 256 threads");
  __shared__ float xs[BK][BM + 1];
  __shared__ float wsm[BK][BN];
  const int m0 = blockIdx.y * BM;
  const int c0 = blockIdx.x * BN;
  const int kbeg = blockIdx.z * KS;
  const int kend = min(K, kbeg + KS);
  const int tn = threadIdx.x % (BN/TN);
  const int tm = threadIdx.x / (BN/TN);
  float acc[TM][TN];
  #pragma unroll
  for (int i = 0; i < TM; ++i)
    #pragma unroll
    for (int j = 0; j < TN; ++j) acc[i][j] = 0.f;

  for (int k0 = kbeg; k0 < kend; k0 += BK) {
    #pragma unroll
    for (int i = threadIdx.x; i < BM*BK; i += NTH) {
      int m = i / BK, k = i % BK;
      xs[k][m] = X[(long)(m0 + m)*K + k0 + k];
    }
    #pragma unroll
    for (int i = threadIdx.x; i < BK*BN; i += NTH) {
      int k = i / BN, c = i % BN;
      wsm[k][c] = W[(long)(k0 + k)*C + c0 + c];
    }
    __syncthreads();
    #pragma unroll
    for (int k = 0; k < BK; ++k) {
      float xv[TM], wv[TN];
      #pragma unroll
      for (int i = 0; i < TM; ++i) xv[i] = xs[k][tm*TM + i];
      #pragma unroll
      for (int j = 0; j < TN; ++j) wv[j] = wsm[k][tn*TN + j];
      #pragma unroll
      for (int i = 0; i < TM; ++i)
        #pragma unroll
        for (int j = 0; j < TN; ++j) acc[i][j] = fmaf(xv[i], wv[j], acc[i][j]);
    }
    __syncthreads();
  }
  float* pz = P + (size_t)blockIdx.z * MR * C;
  #pragma unroll
  for (int i = 0; i < TM; ++i) {
    float* yr = pz + (long)(m0 + tm*TM + i)*C + c0 + tn*TN;
    #pragma unroll
    for (int j = 0; j < TN; ++j) yr[j] = acc[i][j];
  }
}

// reduce NZ partials + bias + optional relu
__global__ void k_redux(const float* __restrict__ P, const float* __restrict__ bias,
                        float* __restrict__ Y, long total, int C, int NZ, int relu) {
  long o = blockIdx.x*256L + threadIdx.x;
  if (o >= total) return;
  float v = bias[(int)(o % C)];
  for (int z = 0; z < NZ; ++z) v += P[(size_t)z*total + o];
  if (relu) v = fmaxf(v, 0.f);
  Y[o] = v;
}

// =================================================================
// split-K f32 GEMM with atomics (kept for tiny fc1)
// =================================================================
template<int BM, int BN, int BK, int TM, int TN>
__global__ void k_gemm_sk(const float* __restrict__ X, const float* __restrict__ W,
                          float* __restrict__ Y, int K, int C, int KS) {
  constexpr int NTH = (BM/TM)*(BN/TN);
  static_assert(NTH == 256, "block must be 256 threads");
  __shared__ float xs[BK][BM + 1];
  __shared__ float wsm[BK][BN];
  const int m0 = blockIdx.y * BM;
  const int c0 = blockIdx.x * BN;
  const int kbeg = blockIdx.z * KS;
  const int kend = min(K, kbeg + KS);
  const int tn = threadIdx.x % (BN/TN);
  const int tm = threadIdx.x / (BN/TN);
  float acc[TM][TN];
  #pragma unroll
  for (int i = 0; i < TM; ++i)
    #pragma unroll
    for (int j = 0; j < TN; ++j) acc[i][j] = 0.f;

  for (int k0 = kbeg; k0 < kend; k0 += BK) {
    #pragma unroll
    for (int i = threadIdx.x; i < BM*BK; i += NTH) {
      int m = i / BK, k = i % BK;
      xs[k][m] = X[(long)(m0 + m)*K + k0 + k];
    }
    #pragma unroll
    for (int i = threadIdx.x; i < BK*BN; i += NTH) {
      int k = i / BN, c = i % BN;
      wsm[k][c] = W[(long)(k0 + k)*C + c0 + c];
    }
    __syncthreads();
    #pragma unroll
    for (int k = 0; k < BK; ++k) {
      float xv[TM], wv[TN];
      #pragma unroll
      for (int i = 0; i < TM; ++i) xv[i] = xs[k][tm*TM + i];
      #pragma unroll
      for (int j = 0; j < TN; ++j) wv[j] = wsm[k][tn*TN + j];
      #pragma unroll
      for (int i = 0; i < TM; ++i)
        #pragma unroll
        for (int j = 0; j < TN; ++j) acc[i][j] = fmaf(xv[i], wv[j], acc[i][j]);
    }
    __syncthreads();
  }
  #pragma unroll
  for (int i = 0; i < TM; ++i) {
    float* yr = Y + (long)(m0 + tm*TM + i)*C + c0 + tn*TN;
    #pragma unroll
    for (int j = 0; j < TN; ++j) atomicAdd(&yr[j], acc[i][j]);
  }
}

// bias + optional relu, in place over [rows*C]
__global__ void k_bias_relu(float* __restrict__ Y, const float* __restrict__ bias,
                            long total, int C, int relu) {
  long o = blockIdx.x*256L + threadIdx.x;
  if (o >= total) return;
  int c = (int)(o % C);
  float v = Y[o] + bias[c];
  if (relu) v = fmaxf(v, 0.f);
  Y[o] = v;
}

// =================================================================
// per-node attention terms, wave-per-node (coalesced loads + shfl reduce)
// =================================================================
template<int H, int CH>
__global__ void k_nodeterms_w(const float* __restrict__ hf, const float* __restrict__ a_s,
                              const float* __restrict__ a_d, float* __restrict__ as_o,
                              float* __restrict__ ad_o) {
  constexpr int F = H * CH;
  constexpr int NJ = (F + 63) / 64;
  int wid = (int)((blockIdx.x*256L + threadIdx.x) >> 6);
  int lane = threadIdx.x & 63;
  if (wid >= NN) return;
  const float* hr = hf + (long)wid * F;
  float s1[H], s2[H];
  #pragma unroll
  for (int h = 0; h < H; ++h) { s1[h] = 0.f; s2[h] = 0.f; }
  #pragma unroll
  for (int j = 0; j < NJ; ++j) {
    int c = j*64 + lane;
    if ((F % 64 == 0) || c < F) {
      int h = c / CH;
      float v = hr[c];
      s1[h] = fmaf(v, a_s[c], s1[h]);
      s2[h] = fmaf(v, a_d[c], s2[h]);
    }
  }
  #pragma unroll
  for (int h = 0; h < H; ++h) {
    #pragma unroll
    for (int off = 1; off < 64; off <<= 1) {
      s1[h] += __shfl_xor(s1[h], off, 64);
      s2[h] += __shfl_xor(s2[h], off, 64);
    }
  }
  if (lane == 0) {
    #pragma unroll
    for (int h = 0; h < H; ++h) {
      as_o[(long)wid*H + h] = s1[h];
      ad_o[(long)wid*H + h] = s2[h];
    }
  }
}

// per-edge attention logit with leaky_relu(0.2), written directly in CSR
// order via csr_pos. e >= EE are self loops.
template<int H>
__global__ void k_edge_attn(const int* __restrict__ ei, const float* __restrict__ ea,
                            const int* __restrict__ csr_pos,
                            const float* __restrict__ asb, const float* __restrict__ adb,
                            const float* __restrict__ M, const float* __restrict__ aeself,
                            float* __restrict__ ac) {
  long e = blockIdx.x*256L + threadIdx.x;
  if (e >= (long)EN) return;
  int s, d;
  float av[H];
  if (e < EE) {
    s = ei[e]; d = ei[EE + e];
    float er[5];
    #pragma unroll
    for (int j = 0; j < 5; ++j) er[j] = ea[e*5 + j];
    #pragma unroll
    for (int h = 0; h < H; ++h) {
      float t = 0.f;
      #pragma unroll
      for (int j = 0; j < 5; ++j) t = fmaf(er[j], M[j*H + h], t);
      av[h] = t;
    }
  } else {
    s = d = (int)(e - EE);
    #pragma unroll
    for (int h = 0; h < H; ++h) av[h] = aeself[h];
  }
  long p = csr_pos[e];
  #pragma unroll
  for (int h = 0; h < H; ++h) {
    float v = asb[s*H + h] + adb[d*H + h] + av[h];
    ac[p*H + h] = (v > 0.f) ? v : 0.2f * v;
  }
}

// per-dst softmax stats: amax[h], rinv[h] (one wave per dst)
template<int H>
__global__ void k_stats(const int* __restrict__ rowptr, const float* __restrict__ ac,
                        float* __restrict__ amaxo, float* __restrict__ rinvo) {
  int wid = (int)((blockIdx.x*256L + threadIdx.x) >> 6);
  int lane = threadIdx.x & 63;
  if (wid >= NN) return;
  int row0 = rowptr[wid], row1 = rowptr[wid + 1];
  float amax[H], asum[H];
  #pragma unroll
  for (int h = 0; h < H; ++h) amax[h] = -1e30f;
  for (int p = row0 + lane; p < row1; p += 64) {
    #pragma unroll
    for (int h = 0; h < H; ++h) amax[h] = fmaxf(amax[h], ac[(long)p*H + h]);
  }
  #pragma unroll
  for (int h = 0; h < H; ++h)
    for (int off = 1; off < 64; off <<= 1) amax[h] = fmaxf(amax[h], __shfl_xor(amax[h], off, 64));
  #pragma unroll
  for (int h = 0; h < H; ++h) asum[h] = 0.f;
  for (int p = row0 + lane; p < row1; p += 64) {
    #pragma unroll
    for (int h = 0; h < H; ++h) asum[h] += __expf(ac[(long)p*H + h] - amax[h]);
  }
  #pragma unroll
  for (int h = 0; h < H; ++h)
    for (int off = 1; off < 64; off <<= 1) asum[h] += __shfl_xor(asum[h], off, 64);
  if (lane == 0) {
    #pragma unroll
    for (int h = 0; h < H; ++h) {
      amaxo[(long)wid*H + h] = amax[h];
      rinvo[(long)wid*H + h] = 1.f / (asum[h] + 1e-16f);
    }
  }
}

// normalize logits -> alpha, in place (lane-parallel over CSR slots)
template<int H>
__global__ void k_alpha(const int* __restrict__ csr_dst, const float* __restrict__ amaxb,
                        const float* __restrict__ rinvb, float* __restrict__ ac) {
  long p = blockIdx.x*256L + threadIdx.x;
  if (p >= (long)EN) return;
  int d = csr_dst[p];
  #pragma unroll
  for (int h = 0; h < H; ++h)
    ac[p*H + h] = __expf(ac[p*H + h] - amaxb[(long)d*H + h]) * rinvb[(long)d*H + h];
}

// ------------- CSR build -------------
__global__ void k_deg(const int* __restrict__ ei, int* __restrict__ deg) {
  long e = blockIdx.x*256L + threadIdx.x;
  if (e >= (long)EN) return;
  int d = (e < EE) ? ei[EE + e] : (int)(e - EE);
  atomicAdd(&deg[d], 1);
}

__global__ void k_scan(const int* __restrict__ deg, int* __restrict__ rowptr,
                       int* __restrict__ cursor) {
  __shared__ int ps[256];
  int tid = threadIdx.x;
  int base = tid * 128;           // 256*128 = 32768 = NN
  int s = 0;
  for (int i = 0; i < 128; ++i) s += deg[base + i];
  ps[tid] = s;
  __syncthreads();
  for (int off = 1; off < 256; off <<= 1) {
    int v = (tid >= off) ? ps[tid - off] : 0;
    __syncthreads();
    ps[tid] += v;
    __syncthreads();
  }
  int run = ps[tid] - s;          // exclusive prefix
  for (int i = 0; i < 128; ++i) {
    rowptr[base + i] = run;
    cursor[base + i] = run;
    run += deg[base + i];
  }
  if (tid == 255) rowptr[NN] = run;
}

__global__ void k_scatter(const int* __restrict__ ei, int* __restrict__ cursor,
                          int* __restrict__ csr_src, int* __restrict__ csr_pos,
                          int* __restrict__ csr_dst) {
  long e = blockIdx.x*256L + threadIdx.x;
  if (e >= (long)EN) return;
  int s, d;
  if (e < EE) { s = ei[e]; d = ei[EE + e]; }
  else        { s = d = (int)(e - EE); }
  int p = atomicAdd(&cursor[d], 1);
  csr_src[p] = s;
  csr_dst[p] = d;
  csr_pos[e] = p;
}

// =================================================================
// GAT aggregation: bf16 feature gather, 2 elements/lane (u32 loads),
// wave per dst, XCD-pinned graph swizzle, edge loop unrolled x4.
// ACT: 0=elu, 1=relu. OBF16: bf16 output.
// =================================================================
template<int H, int CH, int ACT, bool OBF16>
__global__ void k_gat_aggr(const int* __restrict__ rowptr, const int* __restrict__ csr_src,
                           const float* __restrict__ ac, const u16* __restrict__ hb,
                           const float* __restrict__ bias, void* __restrict__ outv) {
  int bid = blockIdx.x;
  int x = bid & 7;
  int r = bid >> 3;
  int s = r & 31;
  int c = r >> 5;
  int g = c*8 + x;
  int wid = g*128 + s*4 + (int)(threadIdx.x >> 6);
  int lane = threadIdx.x & 63;
  int row0 = rowptr[wid], row1 = rowptr[wid + 1];
  constexpr int F = H * CH;            // even; pairs never straddle a head (CH even)
  constexpr int NJ = (F + 127) / 128;  // 128 elements (64 lanes x 2) per chunk
  float accL[NJ], accH[NJ];
  #pragma unroll
  for (int j = 0; j < NJ; ++j) { accL[j] = 0.f; accH[j] = 0.f; }
  int p = row0;
  for (; p + 4 <= row1; p += 4) {
    int sidx[4];
    float al[4][H];
    #pragma unroll
    for (int u = 0; u < 4; ++u) sidx[u] = csr_src[p + u];
    #pragma unroll
    for (int u = 0; u < 4; ++u)
      #pragma unroll
      for (int h = 0; h < H; ++h) al[u][h] = ac[(long)(p + u)*H + h];
    #pragma unroll
    for (int j = 0; j < NJ; ++j) {
      int idx0 = j*128 + 2*lane;
      if ((F % 128 == 0) || idx0 < F) {
        int h = idx0 / CH;
        #pragma unroll
        for (int u = 0; u < 4; ++u) {
          unsigned v = *(const unsigned*)&hb[(long)sidx[u]*F + idx0];
          float lo = __uint_as_float(v << 16);
          float hi = __uint_as_float(v & 0xffff0000u);
          accL[j] = fmaf(al[u][h], lo, accL[j]);
          accH[j] = fmaf(al[u][h], hi, accH[j]);
        }
      }
    }
  }
  for (; p < row1; ++p) {
    int src = csr_src[p];
    #pragma unroll
    for (int j = 0; j < NJ; ++j) {
      int idx0 = j*128 + 2*lane;
      if ((F % 128 == 0) || idx0 < F) {
        int h = idx0 / CH;
        float alv = ac[(long)p*H + h];
        unsigned v = *(const unsigned*)&hb[(long)src*F + idx0];
        accL[j] = fmaf(alv, __uint_as_float(v << 16), accL[j]);
        accH[j] = fmaf(alv, __uint_as_float(v & 0xffff0000u), accH[j]);
      }
    }
  }
  #pragma unroll
  for (int j = 0; j < NJ; ++j) {
    int idx0 = j*128 + 2*lane;
    if ((F % 128 == 0) || idx0 < F) {
      float vL = accL[j] + bias[idx0];
      float vH = accH[j] + bias[idx0 + 1];
      if (ACT == 0) {
        vL = (vL > 0.f) ? vL : expm1f(vL);
        vH = (vH > 0.f) ? vH : expm1f(vH);
      } else {
        vL = fmaxf(vL, 0.f);
        vH = fmaxf(vH, 0.f);
      }
      if (OBF16) {
        unsigned w = (unsigned)f2b(vL) | ((unsigned)f2b(vH) << 16);
        *(unsigned*)&((u16*)outv)[(long)wid * F + idx0] = w;
      } else {
        float* o = (float*)outv + (long)wid * F + idx0;
        o[0] = vL; o[1] = vH;
      }
    }
  }
}

// graph max pool (relu'd input >= 0, pooled pre-zeroed)
__global__ void k_pool(const float* __restrict__ g2o, const int* __restrict__ batch,
                       unsigned int* __restrict__ pooled) {
  long o = blockIdx.x*256L + threadIdx.x;
  if (o >= (long)NN * 96) return;
  int n = (int)(o / 96), c = (int)(o % 96);
  atomicMax(&pooled[batch[n]*96 + c], __float_as_uint(g2o[o]));
}

__global__ void k_concat(const float* __restrict__ cd, const float* __restrict__ ct,
                         const float* __restrict__ gfc, float* __restrict__ xc) {
  int t = blockIdx.x*256 + threadIdx.x;
  if (t >= NB*288) return;
  int b = t / 288, c = t % 288;
  float v = (c < 96) ? cd[b*96 + c] : (c < 192) ? ct[b*96 + (c-96)] : gfc[b*96 + (c-192)];
  xc[t] = v;
}

// final 512-dot per row
__global__ void k_final(const float* __restrict__ x, const float* __restrict__ w,
                        const float* __restrict__ b, float* __restrict__ out) {
  int wid = (int)((blockIdx.x*256L + threadIdx.x) >> 6);
  int lane = threadIdx.x & 63;
  if (wid >= NB) return;
  const float* xr = x + (long)wid*512;
  float s = 0.f;
  for (int k = lane; k < 512; k += 64) s = fmaf(xr[k], w[k], s);
  for (int off = 1; off < 64; off <<= 1) s += __shfl_xor(s, off, 64);
  if (lane == 0) out[wid] = s + b[0];
}

// =================================================================
extern "C" void kernel_launch(void* const* d_in, const int* in_sizes, int n_in,
                              void* d_out, int out_size, void* d_ws, size_t ws_size,
                              hipStream_t stream) {
  const int*   xd     = (const int*)  d_in[0];
  const int*   xt     = (const int*)  d_in[1];
  const float* ax     = (const float*)d_in[2];
  const int*   ei     = (const int*)  d_in[3];
  const float* ea     = (const float*)d_in[4];
  const int*   batch  = (const int*)  d_in[5];
  const float* emb_xd = (const float*)d_in[6];
  const float* emb_xt = (const float*)d_in[7];
  const float* wd1 = (const float*)d_in[8];  const float* bd1 = (const float*)d_in[9];
  const float* wd2 = (const float*)d_in[10]; const float* bd2 = (const float*)d_in[11];
  const float* wd3 = (const float*)d_in[12]; const float* bd3 = (const float*)d_in[13];
  const float* wt1 = (const float*)d_in[14]; const float* bt1 = (const float*)d_in[15];
  const float* wt2 = (const float*)d_in[16]; const float* bt2 = (const float*)d_in[17];
  const float* wt3 = (const float*)d_in[18]; const float* bt3 = (const float*)d_in[19];
  const float* g1_w  = (const float*)d_in[20]; const float* g1_as = (const float*)d_in[21];
  const float* g1_ad = (const float*)d_in[22]; const float* g1_we = (const float*)d_in[23];
  const float* g1_ae = (const float*)d_in[24]; const float* g1_b  = (const float*)d_in[25];
  const float* g2_w  = (const float*)d_in[26]; const float* g2_as = (const float*)d_in[27];
  const float* g2_ad = (const float*)d_in[28]; const float* g2_we = (const float*)d_in[29];
  const float* g2_ae = (const float*)d_in[30]; const float* g2_b  = (const float*)d_in[31];
  const float* fc1_w = (const float*)d_in[32]; const float* fc1_b = (const float*)d_in[33];
  const float* c1_w = (const float*)d_in[34]; const float* c1_b = (const float*)d_in[35];
  const float* c2_w = (const float*)d_in[36]; const float* c2_b = (const float*)d_in[37];
  const float* c3_w = (const float*)d_in[38]; const float* c3_b = (const float*)d_in[39];
  const float* c4_w = (const float*)d_in[40]; const float* c4_b = (const float*)d_in[41];
  float* out = (float*)d_out;

  char* ws = (char*)d_ws;
  auto F = [&](size_t off) { return (float*)(ws + off); };
  auto I = [&](size_t off) { return (int*)(ws + off); };
  auto U = [&](size_t off) { return (unsigned int*)(ws + off); };
  auto H = [&](size_t off) { return (u16*)(ws + off); };

  // ---- zero-init the atomically-updated buffers ----
  hipMemsetAsync(ws + OFF_CB,   0, 64*sizeof(float), stream);
  hipMemsetAsync(ws + OFF_DEG,  0, NN*sizeof(int),   stream);
  hipMemsetAsync(ws + OFF_CD,   0, NB*96*sizeof(float), stream);
  hipMemsetAsync(ws + OFF_CT,   0, NB*96*sizeof(float), stream);
  hipMemsetAsync(ws + OFF_POOL, 0, NB*96*sizeof(float), stream);
  hipMemsetAsync(ws + OFF_GFC,  0, NB*96*sizeof(float), stream);

  // ---- tables / weight converts ----
  k_tables<<<(8320 + 6656 + 30 + 255)/256, 256, 0, stream>>>(
      wd1, emb_xd, wt1, emb_xt, g1_we, g1_ae, g2_we, g2_ae,
      F(OFF_FD), F(OFF_FT), F(OFF_CB));
  k_wcvt<<<(8192 + 24576 + 16384 + 49152 + 30720 + 255)/256, 256, 0, stream>>>(
      wd2, wd3, wt2, wt3, g2_w,
      H(OFF_WD2B), H(OFF_WD3B), H(OFF_WT2B), H(OFF_WT3B), H(OFF_W2GB));
  k_easum<<<256, 256, 0, stream>>>(ea, F(OFF_CB));
  k_finalize<<<1, 64, 0, stream>>>(F(OFF_CB));

  // ---- drug conv branch (bf16 MFMA): 100 -> 97 -> 94 -> 91 -> maxpool ----
  k_conv1t<4,65><<<dim3((97 + 15)/16, NB), 512, 0, stream>>>(
      xd, F(OFF_FD), bd1, H(OFF_A), 100, 97);
  k_convmfma<32,4,64,2,false><<<dim3(1, NB), 512, 0, stream>>>(
      H(OFF_A), H(OFF_WD2B), bd2, H(OFF_B), nullptr, 97, 94);
  k_convmfma<64,4,96,3,true><<<dim3(1, NB), 512, 0, stream>>>(
      H(OFF_B), H(OFF_WD3B), bd3, nullptr, U(OFF_CD), 94, 91);

  // ---- target conv branch (bf16 MFMA): 1000 -> 993 -> 986 -> 979 -> maxpool ----
  k_conv1t<8,26><<<dim3((993 + 15)/16, NB), 512, 0, stream>>>(
      xt, F(OFF_FT), bt1, H(OFF_A), 1000, 993);
  k_convmfma<32,8,64,2,false><<<dim3(4, NB), 512, 0, stream>>>(
      H(OFF_A), H(OFF_WT2B), bt2, H(OFF_B), nullptr, 993, 986);
  k_convmfma<64,8,96,3,true><<<dim3(4, NB), 512, 0, stream>>>(
      H(OFF_B), H(OFF_WT3B), bt3, nullptr, U(OFF_CT), 986, 979);

  // ---- CSR build ----
  k_deg<<<(EN + 255)/256, 256, 0, stream>>>(ei, I(OFF_DEG));
  k_scan<<<1, 256, 0, stream>>>(I(OFF_DEG), I(OFF_ROWP), I(OFF_CUR));
  k_scatter<<<(EN + 255)/256, 256, 0, stream>>>(
      ei, I(OFF_CUR), I(OFF_CSRS), I(OFF_CSRP), I(OFF_CSRD));

  // ---- GAT layer 1 ----
  k_gemm<64,64,24,4,4><<<dim3(320/64, NN/64), 256, 0, stream>>>(
      ax, g1_w, F(OFF_A), H(OFF_H1B), 24, 320);
  k_nodeterms_w<5,64><<<NN/4, 256, 0, stream>>>(
      F(OFF_A), g1_as, g1_ad, F(OFF_AS1), F(OFF_AD1));
  k_edge_attn<5><<<(EN + 255)/256, 256, 0, stream>>>(
      ei, ea, I(OFF_CSRP), F(OFF_AS1), F(OFF_AD1), F(OFF_CB), F(OFF_CB) + 35, F(OFF_AC));
  k_stats<5><<<NN/4, 256, 0, stream>>>(
      I(OFF_ROWP), F(OFF_AC), F(OFF_AS1), F(OFF_AD1));   // reuse AS1/AD1 for amax/rinv
  k_alpha<5><<<(EN + 255)/256, 256, 0, stream>>>(
      I(OFF_CSRD), F(OFF_AS1), F(OFF_AD1), F(OFF_AC));
  k_gat_aggr<5,64,0,true><<<NN/4, 256, 0, stream>>>(
      I(OFF_ROWP), I(OFF_CSRS), F(OFF_AC), H(OFF_H1B), g1_b, (void*)H(OFF_B));

  // ---- GAT layer 2 (h2 via MFMA from bf16 g1o) ----
  k_h2mfma<<<NN/128, 512, 0, stream>>>(H(OFF_B), H(OFF_W2GB), F(OFF_C), H(OFF_H2B));
  k_nodeterms_w<1,96><<<NN/4, 256, 0, stream>>>(
      F(OFF_C), g2_as, g2_ad, F(OFF_AS2), F(OFF_AD2));
  k_edge_attn<1><<<(EN + 255)/256, 256, 0, stream>>>(
      ei, ea, I(OFF_CSRP), F(OFF_AS2), F(OFF_AD2), F(OFF_CB) + 25, F(OFF_CB) + 40, F(OFF_AC));
  k_stats<1><<<NN/4, 256, 0, stream>>>(
      I(OFF_ROWP), F(OFF_AC), F(OFF_AS2), F(OFF_AD2));
  k_alpha<1><<<(EN + 255)/256, 256, 0, stream>>>(
      I(OFF_CSRD), F(OFF_AS2), F(OFF_AD2), F(OFF_AC));
  k_gat_aggr<1,96,1,false><<<NN/4, 256, 0, stream>>>(
      I(OFF_ROWP), I(OFF_CSRS), F(OFF_AC), H(OFF_H2B), g2_b, (void*)F(OFF_G2O));

  // ---- graph pool + fc1 (tiny split-K w/ atomics) ----
  k_pool<<<(int)(((long)NN*96 + 255)/256), 256, 0, stream>>>(
      F(OFF_G2O), batch, U(OFF_POOL));
  k_gemm_sk<64,32,32,4,2><<<dim3(96/32, NB/64, 3), 256, 0, stream>>>(
      F(OFF_POOL), fc1_w, F(OFF_GFC), 96, 96, 32);
  k_bias_relu<<<(NB*96 + 255)/256, 256, 0, stream>>>(
      F(OFF_GFC), fc1_b, (long)NB*96, 96, 1);

  // ---- concat + MLP head (split-K private partials + fused reduce) ----
  k_concat<<<(NB*288 + 255)/256, 256, 0, stream>>>(
      F(OFF_CD), F(OFF_CT), F(OFF_GFC), F(OFF_XC));

  k_gemm_skp<64,64,32,4,4><<<dim3(1024/64, NB/64, 3), 256, 0, stream>>>(
      F(OFF_XC), c1_w, F(OFF_M1P), 288, 1024, 96, NB);
  k_redux<<<(NB*1024 + 255)/256, 256, 0, stream>>>(
      F(OFF_M1P), c1_b, F(OFF_M1B), (long)NB*1024, 1024, 3, 1);

  k_gemm_skp<64,64,32,4,4><<<dim3(1024/64, NB/64, 8), 256, 0, stream>>>(
      F(OFF_M1B), c2_w, F(OFF_M2P), 1024, 1024, 128, NB);
  k_redux<<<(NB*1024 + 255)/256, 256, 0, stream>>>(
      F(OFF_M2P), c2_b, F(OFF_M2B), (long)NB*1024, 1024, 8, 1);

  k_gemm_skp<64,64,32,4,4><<<dim3(512/64, NB/64, 8), 256, 0, stream>>>(
      F(OFF_M2B), c3_w, F(OFF_M3P), 1024, 512, 128, NB);
  k_redux<<<(NB*512 + 255)/256, 256, 0, stream>>>(
      F(OFF_M3P), c3_b, F(OFF_M3B), (long)NB*512, 512, 8, 1);

  k_final<<<(NB*64 + 255)/256, 256, 0, stream>>>(F(OFF_M3B), c4_w, c4_b, out);
}